// Round 1
// baseline (2250.178 us; speedup 1.0000x reference)
//
#include <hip/hip_runtime.h>
#include <math.h>

#define Bsz 8
#define Tsz 1024
#define Dsz 768
#define Hn  12
#define HDs 64
#define Msz (Bsz*Tsz)

// Y[m,o] = sum_d X[m,d]*W[o,d] (+ bias[o]).  X:[M,768] W:[768,768] row-major.
__global__ __launch_bounds__(256) void gemm_xwT_kernel(
    const float* __restrict__ X, const float* __restrict__ W,
    const float* __restrict__ bias, float* __restrict__ Y) {
  const int K = Dsz, N = Dsz;
  __shared__ float Xs[32][68];   // [BK][BM+4] transposed for b128 reads
  __shared__ float Ws[32][68];
  int tid = threadIdx.x;
  int tx = tid & 15, ty = tid >> 4;
  int bm = blockIdx.x * 64;
  int bn = blockIdx.y * 64;
  float acc[4][4] = {};
  for (int k0 = 0; k0 < K; k0 += 32) {
    __syncthreads();
    #pragma unroll
    for (int i = 0; i < 8; ++i) {
      int lin = tid + i * 256;
      int r = lin >> 5;       // 0..63 (tile row)
      int c = lin & 31;       // 0..31 (k within tile)
      Xs[c][r] = X[(size_t)(bm + r) * K + k0 + c];
      Ws[c][r] = W[(size_t)(bn + r) * K + k0 + c];
    }
    __syncthreads();
    #pragma unroll
    for (int kk = 0; kk < 32; ++kk) {
      float4 a = *(const float4*)&Xs[kk][ty * 4];
      float4 b = *(const float4*)&Ws[kk][tx * 4];
      float av[4] = {a.x, a.y, a.z, a.w};
      float bv[4] = {b.x, b.y, b.z, b.w};
      #pragma unroll
      for (int i = 0; i < 4; ++i)
        #pragma unroll
        for (int j = 0; j < 4; ++j)
          acc[i][j] = fmaf(av[i], bv[j], acc[i][j]);
    }
  }
  #pragma unroll
  for (int i = 0; i < 4; ++i) {
    int row = bm + ty * 4 + i;
    int col = bn + tx * 4;
    float4 o;
    o.x = acc[i][0]; o.y = acc[i][1]; o.z = acc[i][2]; o.w = acc[i][3];
    if (bias) {
      o.x += bias[col]; o.y += bias[col + 1];
      o.z += bias[col + 2]; o.w += bias[col + 3];
    }
    *(float4*)&Y[(size_t)row * N + col] = o;
  }
}

// Flash-style causal attention over heads stored interleaved [B,T,D] (D = H*HD).
// Block: 256 threads; one (b,h), 64 q-rows. Thread (qr=tid>>2, c=tid&3).
__global__ __launch_bounds__(256) void attn_kernel(
    const float* __restrict__ Q, const float* __restrict__ Kp,
    const float* __restrict__ Vp, float* __restrict__ ctx) {
  __shared__ float Qs[64][68];
  __shared__ float Ks[64][68];   // reused as P-tile after a barrier
  __shared__ float Vs[64][68];
  int tid = threadIdx.x;
  int bh = blockIdx.y;
  int b = bh / Hn, h = bh % Hn;
  int qt = blockIdx.x;
  int t0 = qt * 64;
  const size_t headoff = (size_t)h * HDs;
  const float* qbase = Q + (size_t)b * Tsz * Dsz + headoff;
  const float* kbase = Kp + (size_t)b * Tsz * Dsz + headoff;
  const float* vbase = Vp + (size_t)b * Tsz * Dsz + headoff;
  int qr = tid >> 2;
  int c  = tid & 3;

  #pragma unroll
  for (int i = 0; i < 16; ++i) {
    int lin = tid + i * 256;
    int r = lin >> 6, d = lin & 63;
    Qs[r][d] = qbase[(size_t)(t0 + r) * Dsz + d];
  }

  float m_run = -INFINITY, l_run = 0.f;
  float acc[16];
  #pragma unroll
  for (int i = 0; i < 16; ++i) acc[i] = 0.f;
  const float scale = 0.125f;  // 1/sqrt(64)

  for (int kt = 0; kt <= qt; ++kt) {
    int k0 = kt * 64;
    __syncthreads();  // previous iteration done with Ks(P)/Vs
    #pragma unroll
    for (int i = 0; i < 16; ++i) {
      int lin = tid + i * 256;
      int r = lin >> 6, d = lin & 63;
      Ks[r][d] = kbase[(size_t)(k0 + r) * Dsz + d];
      Vs[r][d] = vbase[(size_t)(k0 + r) * Dsz + d];
    }
    __syncthreads();

    // scores: s[j] = Q[qr,:]·K[c+4j,:]
    float s[16];
    #pragma unroll
    for (int j = 0; j < 16; ++j) s[j] = 0.f;
    const float4* qrow = (const float4*)&Qs[qr][0];
    #pragma unroll
    for (int d4 = 0; d4 < 16; ++d4) {
      float4 qv = qrow[d4];
      #pragma unroll
      for (int j = 0; j < 16; ++j) {
        float4 kv = *(const float4*)&Ks[c + 4 * j][d4 * 4];
        s[j] = fmaf(qv.x, kv.x, s[j]);
        s[j] = fmaf(qv.y, kv.y, s[j]);
        s[j] = fmaf(qv.z, kv.z, s[j]);
        s[j] = fmaf(qv.w, kv.w, s[j]);
      }
    }

    bool diag = (kt == qt);
    float mloc = -INFINITY;
    #pragma unroll
    for (int j = 0; j < 16; ++j) {
      s[j] *= scale;
      if (diag && (c + 4 * j) > qr) s[j] = -INFINITY;
      mloc = fmaxf(mloc, s[j]);
    }
    mloc = fmaxf(mloc, __shfl_xor(mloc, 1));
    mloc = fmaxf(mloc, __shfl_xor(mloc, 2));
    float m_new = fmaxf(m_run, mloc);
    float f = __expf(m_run - m_new);   // first tile: exp(-inf)=0
    float psum = 0.f;
    #pragma unroll
    for (int j = 0; j < 16; ++j) {
      s[j] = __expf(s[j] - m_new);     // masked -> exp(-inf)=0
      psum += s[j];
    }
    psum += __shfl_xor(psum, 1);
    psum += __shfl_xor(psum, 2);
    l_run = l_run * f + psum;
    m_run = m_new;
    #pragma unroll
    for (int i = 0; i < 16; ++i) acc[i] *= f;

    __syncthreads();  // everyone done reading Ks
    #pragma unroll
    for (int j = 0; j < 16; ++j) Ks[qr][c + 4 * j] = s[j];
    __syncthreads();  // P visible

    // PV: acc[dd] += sum_kk P[qr,kk] * V[kk, c*16+dd]
    #pragma unroll
    for (int kk = 0; kk < 64; ++kk) {
      float p = Ks[qr][kk];
      const float4* vrow = (const float4*)&Vs[kk][c * 16];
      #pragma unroll
      for (int q4 = 0; q4 < 4; ++q4) {
        float4 vv = vrow[q4];
        acc[q4 * 4 + 0] = fmaf(p, vv.x, acc[q4 * 4 + 0]);
        acc[q4 * 4 + 1] = fmaf(p, vv.y, acc[q4 * 4 + 1]);
        acc[q4 * 4 + 2] = fmaf(p, vv.z, acc[q4 * 4 + 2]);
        acc[q4 * 4 + 3] = fmaf(p, vv.w, acc[q4 * 4 + 3]);
      }
    }
  }

  float inv = 1.f / l_run;
  size_t obase = ((size_t)(b * Tsz + t0 + qr)) * Dsz + headoff + c * 16;
  #pragma unroll
  for (int q4 = 0; q4 < 4; ++q4) {
    float4 o;
    o.x = acc[q4 * 4 + 0] * inv; o.y = acc[q4 * 4 + 1] * inv;
    o.z = acc[q4 * 4 + 2] * inv; o.w = acc[q4 * 4 + 3] * inv;
    *(float4*)&ctx[obase + q4 * 4] = o;
  }
}

extern "C" void kernel_launch(void* const* d_in, const int* in_sizes, int n_in,
                              void* d_out, int out_size, void* d_ws, size_t ws_size,
                              hipStream_t stream) {
  const float* x  = (const float*)d_in[0];
  const float* Wq = (const float*)d_in[1];
  const float* Wk = (const float*)d_in[2];
  const float* Wv = (const float*)d_in[3];
  const float* Wp = (const float*)d_in[4];
  const float* bp = (const float*)d_in[5];
  float* out = (float*)d_out;

  size_t md = (size_t)Msz * Dsz;
  float* q    = (float*)d_ws;
  float* kbuf = q + md;
  float* vbuf = kbuf + md;
  float* ctx  = vbuf + md;

  dim3 gg(Msz / 64, Dsz / 64), bb(256);
  gemm_xwT_kernel<<<gg, bb, 0, stream>>>(x, Wq, nullptr, q);
  gemm_xwT_kernel<<<gg, bb, 0, stream>>>(x, Wk, nullptr, kbuf);
  gemm_xwT_kernel<<<gg, bb, 0, stream>>>(x, Wv, nullptr, vbuf);

  dim3 ga(Tsz / 64, Bsz * Hn);
  attn_kernel<<<ga, 256, 0, stream>>>(q, kbuf, vbuf, ctx);

  gemm_xwT_kernel<<<gg, bb, 0, stream>>>(ctx, Wp, bp, out);
}

// Round 2
// 254.902 us; speedup vs baseline: 8.8276x; 8.8276x over previous
//
#include <hip/hip_runtime.h>
#include <math.h>

#define Bsz 8
#define Tsz 1024
#define Dsz 768
#define Hn  12
#define Msz (Bsz*Tsz)

typedef __attribute__((ext_vector_type(8))) short bf16x8_t;
typedef __attribute__((ext_vector_type(4))) float f32x4_t;

__device__ __forceinline__ unsigned short f2bf(float f) {
  unsigned u = __builtin_bit_cast(unsigned, f);
  u += 0x7FFFu + ((u >> 16) & 1u);   // RNE
  return (unsigned short)(u >> 16);
}

__device__ __forceinline__ void gload16(const void* g, const void* l) {
  __builtin_amdgcn_global_load_lds(
      (const __attribute__((address_space(1))) unsigned int*)g,
      (__attribute__((address_space(3))) unsigned int*)l, 16, 0, 0);
}

// ---------------- fp32 -> bf16 converts ----------------
__global__ __launch_bounds__(256) void cvt_x_kernel(const float* __restrict__ in,
                                                    unsigned short* __restrict__ out) {
  size_t idx = ((size_t)blockIdx.x * 256 + threadIdx.x) * 4;
  float4 v = *(const float4*)(in + idx);
  union { unsigned short u[4]; uint2 w; } t;
  t.u[0] = f2bf(v.x); t.u[1] = f2bf(v.y); t.u[2] = f2bf(v.z); t.u[3] = f2bf(v.w);
  *(uint2*)(out + idx) = t.w;
}

__global__ __launch_bounds__(256) void cvt_w_kernel(
    const float* __restrict__ w0, const float* __restrict__ w1,
    const float* __restrict__ w2, const float* __restrict__ w3,
    unsigned short* __restrict__ o0, unsigned short* __restrict__ o1,
    unsigned short* __restrict__ o2, unsigned short* __restrict__ o3) {
  const float* src; unsigned short* dst;
  switch (blockIdx.y) {
    case 0: src = w0; dst = o0; break;
    case 1: src = w1; dst = o1; break;
    case 2: src = w2; dst = o2; break;
    default: src = w3; dst = o3; break;
  }
  size_t idx = ((size_t)blockIdx.x * 256 + threadIdx.x) * 4;
  float4 v = *(const float4*)(src + idx);
  union { unsigned short u[4]; uint2 w; } t;
  t.u[0] = f2bf(v.x); t.u[1] = f2bf(v.y); t.u[2] = f2bf(v.z); t.u[3] = f2bf(v.w);
  *(uint2*)(dst + idx) = t.w;
}

// ---------------- bf16 MFMA GEMM: Y = X * W^T (+bias) ----------------
// X:[M,768] bf16 row-major, W:[768,768] bf16 row-major ([out,in]).
// MODE 0: Y bf16 [M,768].  MODE 1: Y bf16 transposed per head: [b,h,hd,T].
// MODE 2: Y fp32 [M,768] + bias.
template<int MODE>
__global__ __launch_bounds__(256) void gemm_mfma_kernel(
    const unsigned short* __restrict__ X, const unsigned short* __restrict__ W,
    const float* __restrict__ bias, void* __restrict__ Yv) {
  __shared__ __align__(16) unsigned short As[128 * 32];
  __shared__ __align__(16) unsigned short Bs[128 * 32];
  const int tid = threadIdx.x;
  const int w = tid >> 6, lane = tid & 63;
  const int i = lane & 15, g = lane >> 4;
  const int wr = w >> 1, wc = w & 1;
  const int bm = blockIdx.x * 128, bn = blockIdx.y * 128;

  f32x4_t acc[4][4];
  #pragma unroll
  for (int a = 0; a < 4; ++a)
    #pragma unroll
    for (int b2 = 0; b2 < 4; ++b2)
      #pragma unroll
      for (int r = 0; r < 4; ++r) acc[a][b2][r] = 0.f;

  for (int k0 = 0; k0 < Dsz; k0 += 32) {
    __syncthreads();
    #pragma unroll
    for (int j = 0; j < 2; ++j) {
      const int c = 2 * w + j;
      const int row = 16 * c + (lane >> 2);
      const int cb = (lane & 3) * 16;
      const char* ga = (const char*)X + ((size_t)(bm + row) * Dsz + k0) * 2 + cb;
      gload16(ga, (const char*)As + c * 1024);
      const char* gb = (const char*)W + ((size_t)(bn + row) * Dsz + k0) * 2 + cb;
      gload16(gb, (const char*)Bs + c * 1024);
    }
    __syncthreads();
    bf16x8_t af[4], bfr[4];
    #pragma unroll
    for (int f = 0; f < 4; ++f) {
      af[f]  = *(const bf16x8_t*)&As[(64 * wr + 16 * f + i) * 32 + 8 * g];
      bfr[f] = *(const bf16x8_t*)&Bs[(64 * wc + 16 * f + i) * 32 + 8 * g];
    }
    #pragma unroll
    for (int a = 0; a < 4; ++a)
      #pragma unroll
      for (int b2 = 0; b2 < 4; ++b2)
        acc[a][b2] = __builtin_amdgcn_mfma_f32_16x16x32_bf16(af[a], bfr[b2], acc[a][b2], 0, 0, 0);
  }

  if (MODE == 0) {
    unsigned short* Y = (unsigned short*)Yv;
    #pragma unroll
    for (int fi = 0; fi < 4; ++fi)
      #pragma unroll
      for (int fj = 0; fj < 4; ++fj) {
        const int n = bn + 64 * wc + 16 * fj + i;
        #pragma unroll
        for (int r = 0; r < 4; ++r) {
          const int m = bm + 64 * wr + 16 * fi + 4 * g + r;
          Y[(size_t)m * Dsz + n] = f2bf(acc[fi][fj][r]);
        }
      }
  } else if (MODE == 1) {
    unsigned short* Y = (unsigned short*)Yv;
    #pragma unroll
    for (int fi = 0; fi < 4; ++fi)
      #pragma unroll
      for (int fj = 0; fj < 4; ++fj) {
        const int m0 = bm + 64 * wr + 16 * fi + 4 * g;   // 4-aligned, r=0..3 -> t consecutive
        const int bb = m0 >> 10;
        const int t  = m0 & 1023;
        const int n  = bn + 64 * wc + 16 * fj + i;
        union { unsigned short u[4]; uint2 v; } pk;
        #pragma unroll
        for (int r = 0; r < 4; ++r) pk.u[r] = f2bf(acc[fi][fj][r]);
        *(uint2*)&Y[((size_t)(bb * Dsz + n)) * Tsz + t] = pk.v;
      }
  } else {
    float* Y = (float*)Yv;
    #pragma unroll
    for (int fi = 0; fi < 4; ++fi)
      #pragma unroll
      for (int fj = 0; fj < 4; ++fj) {
        const int n = bn + 64 * wc + 16 * fj + i;
        const float bv = bias[n];
        #pragma unroll
        for (int r = 0; r < 4; ++r) {
          const int m = bm + 64 * wr + 16 * fi + 4 * g + r;
          Y[(size_t)m * Dsz + n] = acc[fi][fj][r] + bv;
        }
      }
  }
}

// ---------------- flash attention, bf16 MFMA ----------------
// Q,K: [B,T,768] bf16.  VT: [B*H*64, T] bf16 (per-head transposed V).
// ctx out: [B,T,768] bf16.
__global__ __launch_bounds__(256) void attn_mfma_kernel(
    const unsigned short* __restrict__ Qm, const unsigned short* __restrict__ Km,
    const unsigned short* __restrict__ Vt, unsigned short* __restrict__ ctx) {
  __shared__ __align__(16) unsigned short Ks[64 * 64];
  __shared__ __align__(16) unsigned short Vs[64 * 64];
  __shared__ __align__(16) unsigned short Ps[4][16 * 72];
  const int tid = threadIdx.x, w = tid >> 6, lane = tid & 63;
  const int i = lane & 15, g = lane >> 4;
  const int qt = blockIdx.x, bh = blockIdx.y;
  const int b = bh / Hn, h = bh % Hn;
  const int t0 = qt * 64;

  // Q fragments (A operand): lane holds Q[row=t0+16w+i][hd = 8g+e (+32*ks)]
  bf16x8_t qa[2];
  {
    const unsigned short* qp = Qm + ((size_t)(b * Tsz + t0 + 16 * w + i) * Dsz + h * 64 + 8 * g);
    qa[0] = *(const bf16x8_t*)qp;
    qa[1] = *(const bf16x8_t*)(qp + 32);
  }

  f32x4_t o[4];
  #pragma unroll
  for (int fd = 0; fd < 4; ++fd)
    #pragma unroll
    for (int r = 0; r < 4; ++r) o[fd][r] = 0.f;
  float mrun[4] = {-3.0e38f, -3.0e38f, -3.0e38f, -3.0e38f};
  float lrun[4] = {0.f, 0.f, 0.f, 0.f};

  const int srow = lane >> 3;                      // row within 8-row chunk
  const int swl  = 16 * ((lane & 7) ^ srow);       // pre-swizzled source col-byte

  for (int kt = 0; kt <= qt; ++kt) {
    const int k0 = kt * 64;
    __syncthreads();
    #pragma unroll
    for (int j = 0; j < 2; ++j) {
      const int c = w + 4 * j;                     // chunk 0..7
      const int row = 8 * c + srow;
      const char* gk = (const char*)Km +
          ((size_t)(b * Tsz + k0 + row) * Dsz + h * 64) * 2 + swl;
      gload16(gk, (const char*)Ks + c * 1024);
      const char* gv = (const char*)Vt +
          ((size_t)(bh * 64 + row) * Tsz + k0) * 2 + swl;
      gload16(gv, (const char*)Vs + c * 1024);
    }
    __syncthreads();

    // S = Q K^T   (D layout: lane holds S[4g+r][16fj+i])
    f32x4_t s[4];
    #pragma unroll
    for (int fj = 0; fj < 4; ++fj)
      #pragma unroll
      for (int r = 0; r < 4; ++r) s[fj][r] = 0.f;
    #pragma unroll
    for (int ks = 0; ks < 2; ++ks)
      #pragma unroll
      for (int fj = 0; fj < 4; ++fj) {
        const int R = 16 * fj + i;
        const bf16x8_t kb = *(const bf16x8_t*)((const char*)Ks + R * 128 +
                                               ((16 * g + 64 * ks) ^ ((R & 7) << 4)));
        s[fj] = __builtin_amdgcn_mfma_f32_16x16x32_bf16(qa[ks], kb, s[fj], 0, 0, 0);
      }

    // mask + scale + online softmax
    float p[4][4];
    float mx[4] = {-3.0e38f, -3.0e38f, -3.0e38f, -3.0e38f};
    #pragma unroll
    for (int fj = 0; fj < 4; ++fj) {
      const int kidx = k0 + 16 * fj + i;
      #pragma unroll
      for (int r = 0; r < 4; ++r) {
        float v = s[fj][r] * 0.125f;
        const int qidx = t0 + 16 * w + 4 * g + r;
        if (kidx > qidx) v = -1.0e30f;
        p[fj][r] = v;
        mx[r] = fmaxf(mx[r], v);
      }
    }
    #pragma unroll
    for (int r = 0; r < 4; ++r) {
      mx[r] = fmaxf(mx[r], __shfl_xor(mx[r], 1));
      mx[r] = fmaxf(mx[r], __shfl_xor(mx[r], 2));
      mx[r] = fmaxf(mx[r], __shfl_xor(mx[r], 4));
      mx[r] = fmaxf(mx[r], __shfl_xor(mx[r], 8));
    }
    float fs[4];
    #pragma unroll
    for (int r = 0; r < 4; ++r) {
      const float mn = fmaxf(mrun[r], mx[r]);
      fs[r] = __expf(mrun[r] - mn);
      mrun[r] = mn;
    }
    float rs[4] = {0.f, 0.f, 0.f, 0.f};
    #pragma unroll
    for (int fj = 0; fj < 4; ++fj)
      #pragma unroll
      for (int r = 0; r < 4; ++r) {
        p[fj][r] = __expf(p[fj][r] - mrun[r]);
        rs[r] += p[fj][r];
      }
    #pragma unroll
    for (int r = 0; r < 4; ++r) {
      rs[r] += __shfl_xor(rs[r], 1);
      rs[r] += __shfl_xor(rs[r], 2);
      rs[r] += __shfl_xor(rs[r], 4);
      rs[r] += __shfl_xor(rs[r], 8);
      lrun[r] = lrun[r] * fs[r] + rs[r];
    }
    #pragma unroll
    for (int fd = 0; fd < 4; ++fd)
      #pragma unroll
      for (int r = 0; r < 4; ++r) o[fd][r] *= fs[r];

    // stage P (bf16) to per-wave LDS, re-layout D->A
    #pragma unroll
    for (int fj = 0; fj < 4; ++fj)
      #pragma unroll
      for (int r = 0; r < 4; ++r)
        Ps[w][(4 * g + r) * 72 + 16 * fj + i] = f2bf(p[fj][r]);

    // O += P * V   (A from Ps, B from Vs rows = d, cols = keys)
    #pragma unroll
    for (int ks = 0; ks < 2; ++ks) {
      const bf16x8_t pa = *(const bf16x8_t*)&Ps[w][i * 72 + 32 * ks + 8 * g];
      #pragma unroll
      for (int fd = 0; fd < 4; ++fd) {
        const int R = 16 * fd + i;
        const bf16x8_t vb = *(const bf16x8_t*)((const char*)Vs + R * 128 +
                                               ((16 * g + 64 * ks) ^ ((R & 7) << 4)));
        o[fd] = __builtin_amdgcn_mfma_f32_16x16x32_bf16(pa, vb, o[fd], 0, 0, 0);
      }
    }
  }

  #pragma unroll
  for (int r = 0; r < 4; ++r) {
    const float inv = 1.f / lrun[r];
    const int qidx = t0 + 16 * w + 4 * g + r;
    #pragma unroll
    for (int fd = 0; fd < 4; ++fd)
      ctx[(size_t)(b * Tsz + qidx) * Dsz + h * 64 + 16 * fd + i] = f2bf(o[fd][r] * inv);
  }
}

extern "C" void kernel_launch(void* const* d_in, const int* in_sizes, int n_in,
                              void* d_out, int out_size, void* d_ws, size_t ws_size,
                              hipStream_t stream) {
  const float* x  = (const float*)d_in[0];
  const float* Wq = (const float*)d_in[1];
  const float* Wk = (const float*)d_in[2];
  const float* Wv = (const float*)d_in[3];
  const float* Wp = (const float*)d_in[4];
  const float* bp = (const float*)d_in[5];
  float* out = (float*)d_out;

  const size_t md = (size_t)Msz * Dsz;     // 6291456
  const size_t wd = (size_t)Dsz * Dsz;     // 589824
  unsigned short* xb   = (unsigned short*)d_ws;
  unsigned short* wqb  = xb + md;
  unsigned short* wkb  = wqb + wd;
  unsigned short* wvb  = wkb + wd;
  unsigned short* wpb  = wvb + wd;
  unsigned short* qb   = wpb + wd;
  unsigned short* kb   = qb + md;
  unsigned short* vtb  = kb + md;
  unsigned short* ctxb = vtb + md;

  cvt_x_kernel<<<md / 1024, 256, 0, stream>>>(x, xb);
  cvt_w_kernel<<<dim3(wd / 1024, 4), 256, 0, stream>>>(Wq, Wk, Wv, Wp, wqb, wkb, wvb, wpb);

  dim3 gg(Msz / 128, Dsz / 128), bb(256);
  gemm_mfma_kernel<0><<<gg, bb, 0, stream>>>(xb, wqb, nullptr, qb);
  gemm_mfma_kernel<0><<<gg, bb, 0, stream>>>(xb, wkb, nullptr, kb);
  gemm_mfma_kernel<1><<<gg, bb, 0, stream>>>(xb, wvb, nullptr, vtb);

  attn_mfma_kernel<<<dim3(Tsz / 64, Bsz * Hn), 256, 0, stream>>>(qb, kb, vtb, ctxb);

  gemm_mfma_kernel<2><<<gg, bb, 0, stream>>>(ctxb, wpb, bp, out);
}

// Round 4
// 231.544 us; speedup vs baseline: 9.7181x; 1.1009x over previous
//
#include <hip/hip_runtime.h>
#include <math.h>

#define Bsz 8
#define Tsz 1024
#define Dsz 768
#define Hn  12
#define Msz (Bsz*Tsz)
#define NQT (Tsz/64)   // 16 q-tiles of 64 rows

typedef __attribute__((ext_vector_type(8))) short bf16x8_t;
typedef __attribute__((ext_vector_type(4))) float f32x4_t;

__device__ __forceinline__ unsigned short f2bf(float f) {
  unsigned u = __builtin_bit_cast(unsigned, f);
  u += 0x7FFFu + ((u >> 16) & 1u);   // RNE
  return (unsigned short)(u >> 16);
}

__device__ __forceinline__ void gload16(const void* g, const void* l) {
  __builtin_amdgcn_global_load_lds(
      (const __attribute__((address_space(1))) unsigned int*)g,
      (__attribute__((address_space(3))) unsigned int*)l, 16, 0, 0);
}

// ---------------- fp32 -> bf16 converts ----------------
__global__ __launch_bounds__(256) void cvt_x_kernel(const float* __restrict__ in,
                                                    unsigned short* __restrict__ out) {
  size_t idx = ((size_t)blockIdx.x * 256 + threadIdx.x) * 4;
  float4 v = *(const float4*)(in + idx);
  union { unsigned short u[4]; uint2 w; } t;
  t.u[0] = f2bf(v.x); t.u[1] = f2bf(v.y); t.u[2] = f2bf(v.z); t.u[3] = f2bf(v.w);
  *(uint2*)(out + idx) = t.w;
}

__global__ __launch_bounds__(256) void cvt_w_kernel(
    const float* __restrict__ w0, const float* __restrict__ w1,
    const float* __restrict__ w2, const float* __restrict__ w3,
    unsigned short* __restrict__ o0, unsigned short* __restrict__ o1,
    unsigned short* __restrict__ o2, unsigned short* __restrict__ o3) {
  const float* src; unsigned short* dst;
  switch (blockIdx.y) {
    case 0: src = w0; dst = o0; break;
    case 1: src = w1; dst = o1; break;
    case 2: src = w2; dst = o2; break;
    default: src = w3; dst = o3; break;
  }
  size_t idx = ((size_t)blockIdx.x * 256 + threadIdx.x) * 4;
  float4 v = *(const float4*)(src + idx);
  union { unsigned short u[4]; uint2 w; } t;
  t.u[0] = f2bf(v.x); t.u[1] = f2bf(v.y); t.u[2] = f2bf(v.z); t.u[3] = f2bf(v.w);
  *(uint2*)(dst + idx) = t.w;
}

// ---------------- fused QKV GEMM: [Q|K|V] = X * Wcat^T ----------------
// X:[M,768] bf16, Wcat:[2304,768] bf16 (Wq,Wk,Wv stacked).
// Columns 0..767 -> Yq (bf16 [M,768]); 768..1535 -> Yk; 1536..2303 -> Yvt
// (per-head transposed: [b,h,hd,T]).
__global__ __launch_bounds__(256) void gemm_qkv_kernel(
    const unsigned short* __restrict__ X, const unsigned short* __restrict__ Wcat,
    unsigned short* __restrict__ Yq, unsigned short* __restrict__ Yk,
    unsigned short* __restrict__ Yvt) {
  __shared__ __align__(16) unsigned short As[128 * 32];
  __shared__ __align__(16) unsigned short Bs[128 * 32];
  const int tid = threadIdx.x;
  const int w = tid >> 6, lane = tid & 63;
  const int i = lane & 15, g = lane >> 4;
  const int wr = w >> 1, wc = w & 1;
  const int bm = blockIdx.x * 128, bn = blockIdx.y * 128;

  f32x4_t acc[4][4];
  #pragma unroll
  for (int a = 0; a < 4; ++a)
    #pragma unroll
    for (int b2 = 0; b2 < 4; ++b2)
      #pragma unroll
      for (int r = 0; r < 4; ++r) acc[a][b2][r] = 0.f;

  for (int k0 = 0; k0 < Dsz; k0 += 32) {
    __syncthreads();
    #pragma unroll
    for (int j = 0; j < 2; ++j) {
      const int c = 2 * w + j;
      const int row = 16 * c + (lane >> 2);
      const int cb = (lane & 3) * 16;
      const char* ga = (const char*)X + ((size_t)(bm + row) * Dsz + k0) * 2 + cb;
      gload16(ga, (const char*)As + c * 1024);
      const char* gb = (const char*)Wcat + ((size_t)(bn + row) * Dsz + k0) * 2 + cb;
      gload16(gb, (const char*)Bs + c * 1024);
    }
    __syncthreads();
    bf16x8_t af[4], bfr[4];
    #pragma unroll
    for (int f = 0; f < 4; ++f) {
      af[f]  = *(const bf16x8_t*)&As[(64 * wr + 16 * f + i) * 32 + 8 * g];
      bfr[f] = *(const bf16x8_t*)&Bs[(64 * wc + 16 * f + i) * 32 + 8 * g];
    }
    #pragma unroll
    for (int a = 0; a < 4; ++a)
      #pragma unroll
      for (int b2 = 0; b2 < 4; ++b2)
        acc[a][b2] = __builtin_amdgcn_mfma_f32_16x16x32_bf16(af[a], bfr[b2], acc[a][b2], 0, 0, 0);
  }

  const int wsel = blockIdx.y / 6;          // 0=Q 1=K 2=V (128 | 768)
  const int nloc = (blockIdx.y % 6) * 128;  // column base within the weight
  if (wsel < 2) {
    unsigned short* Y = wsel ? Yk : Yq;
    #pragma unroll
    for (int fi = 0; fi < 4; ++fi)
      #pragma unroll
      for (int fj = 0; fj < 4; ++fj) {
        const int n = nloc + 64 * wc + 16 * fj + i;
        #pragma unroll
        for (int r = 0; r < 4; ++r) {
          const int m = bm + 64 * wr + 16 * fi + 4 * g + r;
          Y[(size_t)m * Dsz + n] = f2bf(acc[fi][fj][r]);
        }
      }
  } else {
    #pragma unroll
    for (int fi = 0; fi < 4; ++fi)
      #pragma unroll
      for (int fj = 0; fj < 4; ++fj) {
        const int m0 = bm + 64 * wr + 16 * fi + 4 * g;   // r=0..3 -> consecutive t
        const int bb = m0 >> 10;
        const int t  = m0 & 1023;
        const int n  = nloc + 64 * wc + 16 * fj + i;
        union { unsigned short u[4]; uint2 v; } pk;
        #pragma unroll
        for (int r = 0; r < 4; ++r) pk.u[r] = f2bf(acc[fi][fj][r]);
        *(uint2*)&Yvt[((size_t)(bb * Dsz + n)) * Tsz + t] = pk.v;
      }
  }
}

// ---------------- output projection: out = ctx * Wp^T + bp (fp32 out) ----
__global__ __launch_bounds__(256) void gemm_proj_kernel(
    const unsigned short* __restrict__ X, const unsigned short* __restrict__ W,
    const float* __restrict__ bias, float* __restrict__ Y) {
  __shared__ __align__(16) unsigned short As[128 * 32];
  __shared__ __align__(16) unsigned short Bs[128 * 32];
  const int tid = threadIdx.x;
  const int w = tid >> 6, lane = tid & 63;
  const int i = lane & 15, g = lane >> 4;
  const int wr = w >> 1, wc = w & 1;
  const int bm = blockIdx.x * 128, bn = blockIdx.y * 128;

  f32x4_t acc[4][4];
  #pragma unroll
  for (int a = 0; a < 4; ++a)
    #pragma unroll
    for (int b2 = 0; b2 < 4; ++b2)
      #pragma unroll
      for (int r = 0; r < 4; ++r) acc[a][b2][r] = 0.f;

  for (int k0 = 0; k0 < Dsz; k0 += 32) {
    __syncthreads();
    #pragma unroll
    for (int j = 0; j < 2; ++j) {
      const int c = 2 * w + j;
      const int row = 16 * c + (lane >> 2);
      const int cb = (lane & 3) * 16;
      const char* ga = (const char*)X + ((size_t)(bm + row) * Dsz + k0) * 2 + cb;
      gload16(ga, (const char*)As + c * 1024);
      const char* gb = (const char*)W + ((size_t)(bn + row) * Dsz + k0) * 2 + cb;
      gload16(gb, (const char*)Bs + c * 1024);
    }
    __syncthreads();
    bf16x8_t af[4], bfr[4];
    #pragma unroll
    for (int f = 0; f < 4; ++f) {
      af[f]  = *(const bf16x8_t*)&As[(64 * wr + 16 * f + i) * 32 + 8 * g];
      bfr[f] = *(const bf16x8_t*)&Bs[(64 * wc + 16 * f + i) * 32 + 8 * g];
    }
    #pragma unroll
    for (int a = 0; a < 4; ++a)
      #pragma unroll
      for (int b2 = 0; b2 < 4; ++b2)
        acc[a][b2] = __builtin_amdgcn_mfma_f32_16x16x32_bf16(af[a], bfr[b2], acc[a][b2], 0, 0, 0);
  }

  #pragma unroll
  for (int fi = 0; fi < 4; ++fi)
    #pragma unroll
    for (int fj = 0; fj < 4; ++fj) {
      const int n = bn + 64 * wc + 16 * fj + i;
      const float bv = bias[n];
      #pragma unroll
      for (int r = 0; r < 4; ++r) {
        const int m = bm + 64 * wr + 16 * fi + 4 * g + r;
        Y[(size_t)m * Dsz + n] = acc[fi][fj][r] + bv;
      }
    }
}

// ---------------- flash attention, bf16 MFMA, paired q-tiles, KVBLK=128 ----
// Q,K: [B,T,768] bf16.  Vt: [B*H*64, T] bf16.  ctx: [B,T,768] bf16.
// Block = 4 waves, 64 q-rows per tile; handles q-tiles blockIdx.x and
// NQT-1-blockIdx.x sequentially -> every block does exactly 9 kv iterations.
__global__ __launch_bounds__(256) void attn_mfma_kernel(
    const unsigned short* __restrict__ Qm, const unsigned short* __restrict__ Km,
    const unsigned short* __restrict__ Vt, unsigned short* __restrict__ ctx) {
  __shared__ __align__(16) unsigned short Ks[128 * 64];   // [key][hd] 128B rows
  __shared__ __align__(16) unsigned short Vs[64 * 128];   // [hd][key] 256B rows
  __shared__ __align__(16) unsigned short Ps[4][16 * 136];
  const int tid = threadIdx.x, w = tid >> 6, lane = tid & 63;
  const int i = lane & 15, g = lane >> 4;
  const int bh = blockIdx.y, b = bh / Hn, h = bh % Hn;
  const int kr8 = lane >> 3;          // K staging: row within 8-row chunk
  const int kb8 = (lane & 7) * 16;
  const int vr4 = lane >> 4;          // V staging: row within 4-row chunk
  const int vb4 = (lane & 15) * 16;

  for (int tsel = 0; tsel < 2; ++tsel) {
    const int qt = tsel ? (NQT - 1 - (int)blockIdx.x) : (int)blockIdx.x;
    const int t0 = qt * 64;

    bf16x8_t qa[2];
    {
      const unsigned short* qp =
          Qm + ((size_t)(b * Tsz + t0 + 16 * w + i) * Dsz + h * 64 + 8 * g);
      qa[0] = *(const bf16x8_t*)qp;
      qa[1] = *(const bf16x8_t*)(qp + 32);
    }

    f32x4_t o[4];
    #pragma unroll
    for (int fd = 0; fd < 4; ++fd)
      #pragma unroll
      for (int r = 0; r < 4; ++r) o[fd][r] = 0.f;
    float mrun[4] = {-3.0e38f, -3.0e38f, -3.0e38f, -3.0e38f};
    float lrun[4] = {0.f, 0.f, 0.f, 0.f};

    const int nt2 = qt / 2 + 1;
    for (int kt2 = 0; kt2 < nt2; ++kt2) {
      const int k0 = kt2 * 128;
      const bool uh = (k0 + 64) <= (t0 + 63);   // upper 64 keys have any valid
      const int nfj = uh ? 8 : 4;
      const int nks = uh ? 4 : 2;

      __syncthreads();
      #pragma unroll
      for (int j = 0; j < 4; ++j) {
        const int c = 4 * j + w;                 // chunk 0..15
        const int krow = 8 * c + kr8;            // key row 0..127
        const char* gk = (const char*)Km +
            ((size_t)(b * Tsz + k0 + krow) * Dsz + h * 64) * 2 +
            (kb8 ^ ((kr8 & 7) << 4));
        gload16(gk, (const char*)Ks + c * 1024);
        const int vrow = 4 * c + vr4;            // hd row 0..63
        const char* gv = (const char*)Vt +
            ((size_t)(bh * 64 + vrow) * Tsz + k0) * 2 +
            (vb4 ^ ((vrow & 7) << 4));
        gload16(gv, (const char*)Vs + c * 1024);
      }
      __syncthreads();

      // S = Q K^T : lane holds S[q=4g+r][key=16fj+i]
      f32x4_t s[8];
      #pragma unroll
      for (int fj = 0; fj < 8; ++fj) {
        if (fj >= nfj) continue;
        #pragma unroll
        for (int r = 0; r < 4; ++r) s[fj][r] = 0.f;
        #pragma unroll
        for (int ks = 0; ks < 2; ++ks) {
          const int R = 16 * fj + i;
          const bf16x8_t kb = *(const bf16x8_t*)((const char*)Ks + R * 128 +
                                                 ((16 * g + 64 * ks) ^ ((R & 7) << 4)));
          s[fj] = __builtin_amdgcn_mfma_f32_16x16x32_bf16(qa[ks], kb, s[fj], 0, 0, 0);
        }
      }

      // mask + scale + max
      float mx[4] = {-3.0e38f, -3.0e38f, -3.0e38f, -3.0e38f};
      #pragma unroll
      for (int fj = 0; fj < 8; ++fj) {
        if (fj >= nfj) continue;
        const int kidx = k0 + 16 * fj + i;
        #pragma unroll
        for (int r = 0; r < 4; ++r) {
          float v = s[fj][r] * 0.125f;
          if (kidx > t0 + 16 * w + 4 * g + r) v = -1.0e30f;
          s[fj][r] = v;
          mx[r] = fmaxf(mx[r], v);
        }
      }
      #pragma unroll
      for (int r = 0; r < 4; ++r) {
        mx[r] = fmaxf(mx[r], __shfl_xor(mx[r], 1));
        mx[r] = fmaxf(mx[r], __shfl_xor(mx[r], 2));
        mx[r] = fmaxf(mx[r], __shfl_xor(mx[r], 4));
        mx[r] = fmaxf(mx[r], __shfl_xor(mx[r], 8));
      }
      float fs[4];
      #pragma unroll
      for (int r = 0; r < 4; ++r) {
        const float mn = fmaxf(mrun[r], mx[r]);
        fs[r] = __expf(mrun[r] - mn);
        mrun[r] = mn;
      }
      float rs[4] = {0.f, 0.f, 0.f, 0.f};
      #pragma unroll
      for (int fj = 0; fj < 8; ++fj) {
        if (fj >= nfj) continue;
        #pragma unroll
        for (int r = 0; r < 4; ++r) {
          s[fj][r] = __expf(s[fj][r] - mrun[r]);
          rs[r] += s[fj][r];
        }
      }
      #pragma unroll
      for (int r = 0; r < 4; ++r) {
        rs[r] += __shfl_xor(rs[r], 1);
        rs[r] += __shfl_xor(rs[r], 2);
        rs[r] += __shfl_xor(rs[r], 4);
        rs[r] += __shfl_xor(rs[r], 8);
        lrun[r] = lrun[r] * fs[r] + rs[r];
      }
      #pragma unroll
      for (int fd = 0; fd < 4; ++fd)
        #pragma unroll
        for (int r = 0; r < 4; ++r) o[fd][r] *= fs[r];

      // stage P (bf16) per-wave, re-layout D->A
      #pragma unroll
      for (int fj = 0; fj < 8; ++fj) {
        if (fj >= nfj) continue;
        #pragma unroll
        for (int r = 0; r < 4; ++r)
          Ps[w][(4 * g + r) * 136 + 16 * fj + i] = f2bf(s[fj][r]);
      }

      // O += P * V
      #pragma unroll
      for (int ks = 0; ks < 4; ++ks) {
        if (ks >= nks) continue;
        const bf16x8_t pa = *(const bf16x8_t*)&Ps[w][i * 136 + 32 * ks + 8 * g];
        #pragma unroll
        for (int fd = 0; fd < 4; ++fd) {
          const int R = 16 * fd + i;
          const bf16x8_t vb = *(const bf16x8_t*)((const char*)Vs + R * 256 +
                                                 ((16 * g + 64 * ks) ^ ((R & 7) << 4)));
          o[fd] = __builtin_amdgcn_mfma_f32_16x16x32_bf16(pa, vb, o[fd], 0, 0, 0);
        }
      }
    }

    #pragma unroll
    for (int r = 0; r < 4; ++r) {
      const float inv = 1.f / lrun[r];
      const int qidx = t0 + 16 * w + 4 * g + r;
      #pragma unroll
      for (int fd = 0; fd < 4; ++fd)
        ctx[(size_t)(b * Tsz + qidx) * Dsz + h * 64 + 16 * fd + i] =
            f2bf(o[fd][r] * inv);
    }
  }
}

extern "C" void kernel_launch(void* const* d_in, const int* in_sizes, int n_in,
                              void* d_out, int out_size, void* d_ws, size_t ws_size,
                              hipStream_t stream) {
  const float* x  = (const float*)d_in[0];
  const float* Wq = (const float*)d_in[1];
  const float* Wk = (const float*)d_in[2];
  const float* Wv = (const float*)d_in[3];
  const float* Wp = (const float*)d_in[4];
  const float* bp = (const float*)d_in[5];
  float* out = (float*)d_out;

  const size_t md = (size_t)Msz * Dsz;
  const size_t wd = (size_t)Dsz * Dsz;
  unsigned short* xb   = (unsigned short*)d_ws;
  unsigned short* wqb  = xb + md;          // wqb,wkb,wvb contiguous = Wcat[2304][768]
  unsigned short* wkb  = wqb + wd;
  unsigned short* wvb  = wkb + wd;
  unsigned short* wpb  = wvb + wd;
  unsigned short* qb   = wpb + wd;
  unsigned short* kb   = qb + md;
  unsigned short* vtb  = kb + md;
  unsigned short* ctxb = vtb + md;

  cvt_x_kernel<<<md / 1024, 256, 0, stream>>>(x, xb);
  cvt_w_kernel<<<dim3(wd / 1024, 4), 256, 0, stream>>>(Wq, Wk, Wv, Wp, wqb, wkb, wvb, wpb);

  gemm_qkv_kernel<<<dim3(Msz / 128, 18), 256, 0, stream>>>(xb, wqb, qb, kb, vtb);

  attn_mfma_kernel<<<dim3(NQT / 2, Bsz * Hn), 256, 0, stream>>>(qb, kb, vtb, ctxb);

  gemm_proj_kernel<<<dim3(Msz / 128, Dsz / 128), 256, 0, stream>>>(ctxb, wpb, bp, out);
}

// Round 5
// 228.923 us; speedup vs baseline: 9.8294x; 1.0114x over previous
//
#include <hip/hip_runtime.h>
#include <math.h>

#define Bsz 8
#define Tsz 1024
#define Dsz 768
#define Hn  12
#define Msz (Bsz*Tsz)
#define NQT (Tsz/64)   // 16 q-tiles of 64 rows

typedef __attribute__((ext_vector_type(8))) short bf16x8_t;
typedef __attribute__((ext_vector_type(4))) float f32x4_t;

__device__ __forceinline__ unsigned short f2bf(float f) {
  unsigned u = __builtin_bit_cast(unsigned, f);
  u += 0x7FFFu + ((u >> 16) & 1u);   // RNE
  return (unsigned short)(u >> 16);
}

__device__ __forceinline__ void gload16(const void* g, const void* l) {
  __builtin_amdgcn_global_load_lds(
      (const __attribute__((address_space(1))) unsigned int*)g,
      (__attribute__((address_space(3))) unsigned int*)l, 16, 0, 0);
}

// ---------------- fp32 -> bf16 converts ----------------
__global__ __launch_bounds__(256) void cvt_x_kernel(const float* __restrict__ in,
                                                    unsigned short* __restrict__ out) {
  size_t idx = ((size_t)blockIdx.x * 256 + threadIdx.x) * 4;
  float4 v = *(const float4*)(in + idx);
  union { unsigned short u[4]; uint2 w; } t;
  t.u[0] = f2bf(v.x); t.u[1] = f2bf(v.y); t.u[2] = f2bf(v.z); t.u[3] = f2bf(v.w);
  *(uint2*)(out + idx) = t.w;
}

__global__ __launch_bounds__(256) void cvt_w_kernel(
    const float* __restrict__ w0, const float* __restrict__ w1,
    const float* __restrict__ w2, const float* __restrict__ w3,
    unsigned short* __restrict__ o0, unsigned short* __restrict__ o1,
    unsigned short* __restrict__ o2, unsigned short* __restrict__ o3) {
  const float* src; unsigned short* dst;
  switch (blockIdx.y) {
    case 0: src = w0; dst = o0; break;
    case 1: src = w1; dst = o1; break;
    case 2: src = w2; dst = o2; break;
    default: src = w3; dst = o3; break;
  }
  size_t idx = ((size_t)blockIdx.x * 256 + threadIdx.x) * 4;
  float4 v = *(const float4*)(src + idx);
  union { unsigned short u[4]; uint2 w; } t;
  t.u[0] = f2bf(v.x); t.u[1] = f2bf(v.y); t.u[2] = f2bf(v.z); t.u[3] = f2bf(v.w);
  *(uint2*)(dst + idx) = t.w;
}

// ---------------- fused QKV GEMM: [Q|K|V] = X * Wcat^T ----------------
// X:[M,768] bf16, Wcat:[2304,768] bf16 (Wq,Wk,Wv stacked).
// Columns 0..767 -> Yq (bf16 [M,768], PRE-SCALED by 0.125*log2(e));
// 768..1535 -> Yk; 1536..2303 -> Yvt (per-head transposed: [b,h,hd,T]).
__global__ __launch_bounds__(256) void gemm_qkv_kernel(
    const unsigned short* __restrict__ X, const unsigned short* __restrict__ Wcat,
    unsigned short* __restrict__ Yq, unsigned short* __restrict__ Yk,
    unsigned short* __restrict__ Yvt) {
  __shared__ __align__(16) unsigned short As[128 * 32];
  __shared__ __align__(16) unsigned short Bs[128 * 32];
  const int tid = threadIdx.x;
  const int w = tid >> 6, lane = tid & 63;
  const int i = lane & 15, g = lane >> 4;
  const int wr = w >> 1, wc = w & 1;
  const int bm = blockIdx.x * 128, bn = blockIdx.y * 128;

  f32x4_t acc[4][4];
  #pragma unroll
  for (int a = 0; a < 4; ++a)
    #pragma unroll
    for (int b2 = 0; b2 < 4; ++b2)
      #pragma unroll
      for (int r = 0; r < 4; ++r) acc[a][b2][r] = 0.f;

  for (int k0 = 0; k0 < Dsz; k0 += 32) {
    __syncthreads();
    #pragma unroll
    for (int j = 0; j < 2; ++j) {
      const int c = 2 * w + j;
      const int row = 16 * c + (lane >> 2);
      const int cb = (lane & 3) * 16;
      const char* ga = (const char*)X + ((size_t)(bm + row) * Dsz + k0) * 2 + cb;
      gload16(ga, (const char*)As + c * 1024);
      const char* gb = (const char*)Wcat + ((size_t)(bn + row) * Dsz + k0) * 2 + cb;
      gload16(gb, (const char*)Bs + c * 1024);
    }
    __syncthreads();
    bf16x8_t af[4], bfr[4];
    #pragma unroll
    for (int f = 0; f < 4; ++f) {
      af[f]  = *(const bf16x8_t*)&As[(64 * wr + 16 * f + i) * 32 + 8 * g];
      bfr[f] = *(const bf16x8_t*)&Bs[(64 * wc + 16 * f + i) * 32 + 8 * g];
    }
    #pragma unroll
    for (int a = 0; a < 4; ++a)
      #pragma unroll
      for (int b2 = 0; b2 < 4; ++b2)
        acc[a][b2] = __builtin_amdgcn_mfma_f32_16x16x32_bf16(af[a], bfr[b2], acc[a][b2], 0, 0, 0);
  }

  const int wsel = blockIdx.y / 6;          // 0=Q 1=K 2=V
  const int nloc = (blockIdx.y % 6) * 128;  // column base within the weight
  if (wsel < 2) {
    unsigned short* Y = wsel ? Yk : Yq;
    const float sc = wsel ? 1.0f : 0.18033688f;   // Q: 0.125 * log2(e)
    #pragma unroll
    for (int fi = 0; fi < 4; ++fi)
      #pragma unroll
      for (int fj = 0; fj < 4; ++fj) {
        const int n = nloc + 64 * wc + 16 * fj + i;
        #pragma unroll
        for (int r = 0; r < 4; ++r) {
          const int m = bm + 64 * wr + 16 * fi + 4 * g + r;
          Y[(size_t)m * Dsz + n] = f2bf(acc[fi][fj][r] * sc);
        }
      }
  } else {
    #pragma unroll
    for (int fi = 0; fi < 4; ++fi)
      #pragma unroll
      for (int fj = 0; fj < 4; ++fj) {
        const int m0 = bm + 64 * wr + 16 * fi + 4 * g;   // r=0..3 -> consecutive t
        const int bb = m0 >> 10;
        const int t  = m0 & 1023;
        const int n  = nloc + 64 * wc + 16 * fj + i;
        union { unsigned short u[4]; uint2 v; } pk;
        #pragma unroll
        for (int r = 0; r < 4; ++r) pk.u[r] = f2bf(acc[fi][fj][r]);
        *(uint2*)&Yvt[((size_t)(bb * Dsz + n)) * Tsz + t] = pk.v;
      }
  }
}

// ---------------- output projection: out = ctx * Wp^T + bp (fp32 out) ----
__global__ __launch_bounds__(256) void gemm_proj_kernel(
    const unsigned short* __restrict__ X, const unsigned short* __restrict__ W,
    const float* __restrict__ bias, float* __restrict__ Y) {
  __shared__ __align__(16) unsigned short As[128 * 32];
  __shared__ __align__(16) unsigned short Bs[128 * 32];
  const int tid = threadIdx.x;
  const int w = tid >> 6, lane = tid & 63;
  const int i = lane & 15, g = lane >> 4;
  const int wr = w >> 1, wc = w & 1;
  const int bm = blockIdx.x * 128, bn = blockIdx.y * 128;

  f32x4_t acc[4][4];
  #pragma unroll
  for (int a = 0; a < 4; ++a)
    #pragma unroll
    for (int b2 = 0; b2 < 4; ++b2)
      #pragma unroll
      for (int r = 0; r < 4; ++r) acc[a][b2][r] = 0.f;

  for (int k0 = 0; k0 < Dsz; k0 += 32) {
    __syncthreads();
    #pragma unroll
    for (int j = 0; j < 2; ++j) {
      const int c = 2 * w + j;
      const int row = 16 * c + (lane >> 2);
      const int cb = (lane & 3) * 16;
      const char* ga = (const char*)X + ((size_t)(bm + row) * Dsz + k0) * 2 + cb;
      gload16(ga, (const char*)As + c * 1024);
      const char* gb = (const char*)W + ((size_t)(bn + row) * Dsz + k0) * 2 + cb;
      gload16(gb, (const char*)Bs + c * 1024);
    }
    __syncthreads();
    bf16x8_t af[4], bfr[4];
    #pragma unroll
    for (int f = 0; f < 4; ++f) {
      af[f]  = *(const bf16x8_t*)&As[(64 * wr + 16 * f + i) * 32 + 8 * g];
      bfr[f] = *(const bf16x8_t*)&Bs[(64 * wc + 16 * f + i) * 32 + 8 * g];
    }
    #pragma unroll
    for (int a = 0; a < 4; ++a)
      #pragma unroll
      for (int b2 = 0; b2 < 4; ++b2)
        acc[a][b2] = __builtin_amdgcn_mfma_f32_16x16x32_bf16(af[a], bfr[b2], acc[a][b2], 0, 0, 0);
  }

  #pragma unroll
  for (int fi = 0; fi < 4; ++fi)
    #pragma unroll
    for (int fj = 0; fj < 4; ++fj) {
      const int n = bn + 64 * wc + 16 * fj + i;
      const float bv = bias[n];
      #pragma unroll
      for (int r = 0; r < 4; ++r) {
        const int m = bm + 64 * wr + 16 * fi + 4 * g + r;
        Y[(size_t)m * Dsz + n] = acc[fi][fj][r] + bv;
      }
    }
}

// ---------------- flash attention, bf16 MFMA, paired q-tiles, KVBLK=128 ----
// Q (pre-scaled by 0.125*log2e), K: [B,T,768] bf16.  Vt: [B*H*64, T] bf16.
// ctx: [B,T,768] bf16.  LDS: Ks region unioned with P-staging (Ks dead after
// QK^T; one extra barrier before P write) -> 33.8 KB -> 4 blocks/CU.
__global__ __launch_bounds__(256) void attn_mfma_kernel(
    const unsigned short* __restrict__ Qm, const unsigned short* __restrict__ Km,
    const unsigned short* __restrict__ Vt, unsigned short* __restrict__ ctx) {
  __shared__ __align__(16) unsigned short KP[4 * 16 * 136];  // Ks(128x64) U Ps[4][16*136]
  __shared__ __align__(16) unsigned short Vs[64 * 128];      // [hd][key] 256B rows
  unsigned short* Ks = KP;
  const int tid = threadIdx.x, w = tid >> 6, lane = tid & 63;
  const int i = lane & 15, g = lane >> 4;
  const int bh = blockIdx.y, b = bh / Hn, h = bh % Hn;
  const int kr8 = lane >> 3;          // K staging: row within 8-row chunk
  const int kb8 = (lane & 7) * 16;
  const int vr4 = lane >> 4;          // V staging: row within 4-row chunk
  const int vb4 = (lane & 15) * 16;

  for (int tsel = 0; tsel < 2; ++tsel) {
    const int qt = tsel ? (NQT - 1 - (int)blockIdx.x) : (int)blockIdx.x;
    const int t0 = qt * 64;

    bf16x8_t qa[2];
    {
      const unsigned short* qp =
          Qm + ((size_t)(b * Tsz + t0 + 16 * w + i) * Dsz + h * 64 + 8 * g);
      qa[0] = *(const bf16x8_t*)qp;
      qa[1] = *(const bf16x8_t*)(qp + 32);
    }

    f32x4_t o[4];
    #pragma unroll
    for (int fd = 0; fd < 4; ++fd)
      #pragma unroll
      for (int r = 0; r < 4; ++r) o[fd][r] = 0.f;
    float mrun[4] = {-3.0e38f, -3.0e38f, -3.0e38f, -3.0e38f};
    float lrun[4] = {0.f, 0.f, 0.f, 0.f};

    const int nt2 = qt / 2 + 1;
    for (int kt2 = 0; kt2 < nt2; ++kt2) {
      const int k0 = kt2 * 128;
      const bool uh = (k0 + 64) <= (t0 + 63);   // upper 64 keys have any valid
      const int nfj = uh ? 8 : 4;
      const int nks = uh ? 4 : 2;
      const bool dtile = (kt2 == (qt >> 1));    // only tile needing the causal mask

      __syncthreads();
      #pragma unroll
      for (int j = 0; j < 4; ++j) {
        const int c = 4 * j + w;                 // chunk 0..15
        const int krow = 8 * c + kr8;            // key row 0..127
        const char* gk = (const char*)Km +
            ((size_t)(b * Tsz + k0 + krow) * Dsz + h * 64) * 2 +
            (kb8 ^ ((kr8 & 7) << 4));
        gload16(gk, (const char*)Ks + c * 1024);
        const int vrow = 4 * c + vr4;            // hd row 0..63
        const char* gv = (const char*)Vt +
            ((size_t)(bh * 64 + vrow) * Tsz + k0) * 2 +
            (vb4 ^ ((vrow & 7) << 4));
        gload16(gv, (const char*)Vs + c * 1024);
      }
      __syncthreads();

      // S = Q K^T : lane holds S[q=4g+r][key=16fj+i]  (log2-units, pre-scaled Q)
      f32x4_t s[8];
      #pragma unroll
      for (int fj = 0; fj < 8; ++fj) {
        if (fj >= nfj) continue;
        #pragma unroll
        for (int r = 0; r < 4; ++r) s[fj][r] = 0.f;
        #pragma unroll
        for (int ks = 0; ks < 2; ++ks) {
          const int R = 16 * fj + i;
          const bf16x8_t kb = *(const bf16x8_t*)((const char*)Ks + R * 128 +
                                                 ((16 * g + 64 * ks) ^ ((R & 7) << 4)));
          s[fj] = __builtin_amdgcn_mfma_f32_16x16x32_bf16(qa[ks], kb, s[fj], 0, 0, 0);
        }
      }

      // causal mask only on the diagonal tile (block-uniform branch)
      if (dtile) {
        #pragma unroll
        for (int fj = 0; fj < 8; ++fj) {
          if (fj >= nfj) continue;
          const int kidx = k0 + 16 * fj + i;
          #pragma unroll
          for (int r = 0; r < 4; ++r)
            if (kidx > t0 + 16 * w + 4 * g + r) s[fj][r] = -1.0e30f;
        }
      }

      // row max
      float mx[4] = {-3.0e38f, -3.0e38f, -3.0e38f, -3.0e38f};
      #pragma unroll
      for (int fj = 0; fj < 8; ++fj) {
        if (fj >= nfj) continue;
        #pragma unroll
        for (int r = 0; r < 4; ++r) mx[r] = fmaxf(mx[r], s[fj][r]);
      }
      #pragma unroll
      for (int r = 0; r < 4; ++r) {
        mx[r] = fmaxf(mx[r], __shfl_xor(mx[r], 1));
        mx[r] = fmaxf(mx[r], __shfl_xor(mx[r], 2));
        mx[r] = fmaxf(mx[r], __shfl_xor(mx[r], 4));
        mx[r] = fmaxf(mx[r], __shfl_xor(mx[r], 8));
      }

      // defer-max (T13): skip rescale when max growth <= 8 (log2 units)
      bool nd = false;
      #pragma unroll
      for (int r = 0; r < 4; ++r) nd = nd || (mx[r] > mrun[r] + 8.0f);
      if (__any(nd)) {
        #pragma unroll
        for (int r = 0; r < 4; ++r) {
          const float mn = fmaxf(mrun[r], mx[r]);
          const float fs = exp2f(mrun[r] - mn);
          mrun[r] = mn;
          lrun[r] *= fs;
          #pragma unroll
          for (int fd = 0; fd < 4; ++fd) o[fd][r] *= fs;
        }
      }

      float rs[4] = {0.f, 0.f, 0.f, 0.f};
      #pragma unroll
      for (int fj = 0; fj < 8; ++fj) {
        if (fj >= nfj) continue;
        #pragma unroll
        for (int r = 0; r < 4; ++r) {
          s[fj][r] = exp2f(s[fj][r] - mrun[r]);
          rs[r] += s[fj][r];
        }
      }
      #pragma unroll
      for (int r = 0; r < 4; ++r) {
        rs[r] += __shfl_xor(rs[r], 1);
        rs[r] += __shfl_xor(rs[r], 2);
        rs[r] += __shfl_xor(rs[r], 4);
        rs[r] += __shfl_xor(rs[r], 8);
        lrun[r] += rs[r];
      }

      __syncthreads();   // all waves done reading Ks before P overwrites it

      // stage P (bf16) per-wave into the Ks union region, re-layout D->A
      unsigned short* Pw = KP + w * (16 * 136);
      #pragma unroll
      for (int fj = 0; fj < 8; ++fj) {
        if (fj >= nfj) continue;
        #pragma unroll
        for (int r = 0; r < 4; ++r)
          Pw[(4 * g + r) * 136 + 16 * fj + i] = f2bf(s[fj][r]);
      }

      // O += P * V  (own-wave P: no cross-wave barrier needed)
      #pragma unroll
      for (int ks = 0; ks < 4; ++ks) {
        if (ks >= nks) continue;
        const bf16x8_t pa = *(const bf16x8_t*)&Pw[i * 136 + 32 * ks + 8 * g];
        #pragma unroll
        for (int fd = 0; fd < 4; ++fd) {
          const int R = 16 * fd + i;
          const bf16x8_t vb = *(const bf16x8_t*)((const char*)Vs + R * 256 +
                                                 ((16 * g + 64 * ks) ^ ((R & 7) << 4)));
          o[fd] = __builtin_amdgcn_mfma_f32_16x16x32_bf16(pa, vb, o[fd], 0, 0, 0);
        }
      }
    }

    #pragma unroll
    for (int r = 0; r < 4; ++r) {
      const float inv = 1.f / lrun[r];
      const int qidx = t0 + 16 * w + 4 * g + r;
      #pragma unroll
      for (int fd = 0; fd < 4; ++fd)
        ctx[(size_t)(b * Tsz + qidx) * Dsz + h * 64 + 16 * fd + i] =
            f2bf(o[fd][r] * inv);
    }
  }
}

extern "C" void kernel_launch(void* const* d_in, const int* in_sizes, int n_in,
                              void* d_out, int out_size, void* d_ws, size_t ws_size,
                              hipStream_t stream) {
  const float* x  = (const float*)d_in[0];
  const float* Wq = (const float*)d_in[1];
  const float* Wk = (const float*)d_in[2];
  const float* Wv = (const float*)d_in[3];
  const float* Wp = (const float*)d_in[4];
  const float* bp = (const float*)d_in[5];
  float* out = (float*)d_out;

  const size_t md = (size_t)Msz * Dsz;
  const size_t wd = (size_t)Dsz * Dsz;
  unsigned short* xb   = (unsigned short*)d_ws;
  unsigned short* wqb  = xb + md;          // wqb,wkb,wvb contiguous = Wcat[2304][768]
  unsigned short* wkb  = wqb + wd;
  unsigned short* wvb  = wkb + wd;
  unsigned short* wpb  = wvb + wd;
  unsigned short* qb   = wpb + wd;
  unsigned short* kb   = qb + md;
  unsigned short* vtb  = kb + md;
  unsigned short* ctxb = vtb + md;

  cvt_x_kernel<<<md / 1024, 256, 0, stream>>>(x, xb);
  cvt_w_kernel<<<dim3(wd / 1024, 4), 256, 0, stream>>>(Wq, Wk, Wv, Wp, wqb, wkb, wvb, wpb);

  gemm_qkv_kernel<<<dim3(Msz / 128, 18), 256, 0, stream>>>(xb, wqb, qb, kb, vtb);

  attn_mfma_kernel<<<dim3(NQT / 2, Bsz * Hn), 256, 0, stream>>>(qb, kb, vtb, ctxb);

  gemm_proj_kernel<<<dim3(Msz / 128, Dsz / 128), 256, 0, stream>>>(ctxb, wpb, bp, out);
}

// Round 6
// 206.459 us; speedup vs baseline: 10.8989x; 1.1088x over previous
//
#include <hip/hip_runtime.h>
#include <hip/hip_bf16.h>
#include <math.h>

#define Bsz 8
#define Tsz 1024
#define Dsz 768
#define Hn  12
#define Msz (Bsz*Tsz)
#define NQT (Tsz/64)   // 16 q-tiles of 64 rows

typedef __attribute__((ext_vector_type(8))) short bf16x8_t;
typedef __attribute__((ext_vector_type(4))) float f32x4_t;

__device__ __forceinline__ unsigned short f2bf(float f) {
  unsigned u = __builtin_bit_cast(unsigned, f);
  u += 0x7FFFu + ((u >> 16) & 1u);   // RNE (used for input converts)
  return (unsigned short)(u >> 16);
}

__device__ __forceinline__ unsigned short f2bf_fast(float f) {
  __hip_bfloat16 h = __float2bfloat16(f);   // compiler-optimal cvt
  return __builtin_bit_cast(unsigned short, h);
}

__device__ __forceinline__ void gload16(const void* g, const void* l) {
  __builtin_amdgcn_global_load_lds(
      (const __attribute__((address_space(1))) unsigned int*)g,
      (__attribute__((address_space(3))) unsigned int*)l, 16, 0, 0);
}

// ---------------- fused fp32 -> bf16 convert (x + 4 weights) ----------------
#define XBLKS (Msz*Dsz/1024)        // 6144
#define WBLKS (Dsz*Dsz/1024)        // 576
__global__ __launch_bounds__(256) void cvt_all_kernel(
    const float* __restrict__ x,
    const float* __restrict__ w0, const float* __restrict__ w1,
    const float* __restrict__ w2, const float* __restrict__ w3,
    unsigned short* __restrict__ xb,
    unsigned short* __restrict__ o0, unsigned short* __restrict__ o1,
    unsigned short* __restrict__ o2, unsigned short* __restrict__ o3) {
  int bid = blockIdx.x;
  const float* src; unsigned short* dst; size_t blk;
  if (bid < XBLKS) { src = x; dst = xb; blk = bid; }
  else {
    int t = bid - XBLKS;
    int which = t / WBLKS;
    blk = t % WBLKS;
    switch (which) {
      case 0: src = w0; dst = o0; break;
      case 1: src = w1; dst = o1; break;
      case 2: src = w2; dst = o2; break;
      default: src = w3; dst = o3; break;
    }
  }
  size_t idx = (blk * 256 + threadIdx.x) * 4;
  float4 v = *(const float4*)(src + idx);
  union { unsigned short u[4]; uint2 w; } t;
  t.u[0] = f2bf(v.x); t.u[1] = f2bf(v.y); t.u[2] = f2bf(v.z); t.u[3] = f2bf(v.w);
  *(uint2*)(dst + idx) = t.w;
}

// ---------------- fused QKV GEMM: [Q|K|V] = X * Wcat^T ----------------
// Columns 0..767 -> Yq (bf16, PRE-SCALED by 0.125*log2e); 768..1535 -> Yk;
// 1536..2303 -> Yvt (per-head transposed: [b,h,hd,T]).
__global__ __launch_bounds__(256) void gemm_qkv_kernel(
    const unsigned short* __restrict__ X, const unsigned short* __restrict__ Wcat,
    unsigned short* __restrict__ Yq, unsigned short* __restrict__ Yk,
    unsigned short* __restrict__ Yvt) {
  __shared__ __align__(16) unsigned short As[128 * 32];
  __shared__ __align__(16) unsigned short Bs[128 * 32];
  const int tid = threadIdx.x;
  const int w = tid >> 6, lane = tid & 63;
  const int i = lane & 15, g = lane >> 4;
  const int wr = w >> 1, wc = w & 1;
  const int bm = blockIdx.x * 128, bn = blockIdx.y * 128;

  f32x4_t acc[4][4];
  #pragma unroll
  for (int a = 0; a < 4; ++a)
    #pragma unroll
    for (int b2 = 0; b2 < 4; ++b2)
      #pragma unroll
      for (int r = 0; r < 4; ++r) acc[a][b2][r] = 0.f;

  for (int k0 = 0; k0 < Dsz; k0 += 32) {
    __syncthreads();
    #pragma unroll
    for (int j = 0; j < 2; ++j) {
      const int c = 2 * w + j;
      const int row = 16 * c + (lane >> 2);
      const int cb = (lane & 3) * 16;
      gload16((const char*)X + ((size_t)(bm + row) * Dsz + k0) * 2 + cb,
              (const char*)As + c * 1024);
      gload16((const char*)Wcat + ((size_t)(bn + row) * Dsz + k0) * 2 + cb,
              (const char*)Bs + c * 1024);
    }
    __syncthreads();
    bf16x8_t af[4], bfr[4];
    #pragma unroll
    for (int f = 0; f < 4; ++f) {
      af[f]  = *(const bf16x8_t*)&As[(64 * wr + 16 * f + i) * 32 + 8 * g];
      bfr[f] = *(const bf16x8_t*)&Bs[(64 * wc + 16 * f + i) * 32 + 8 * g];
    }
    #pragma unroll
    for (int a = 0; a < 4; ++a)
      #pragma unroll
      for (int b2 = 0; b2 < 4; ++b2)
        acc[a][b2] = __builtin_amdgcn_mfma_f32_16x16x32_bf16(af[a], bfr[b2], acc[a][b2], 0, 0, 0);
  }

  const int wsel = blockIdx.y / 6;
  const int nloc = (blockIdx.y % 6) * 128;
  if (wsel < 2) {
    unsigned short* Y = wsel ? Yk : Yq;
    const float sc = wsel ? 1.0f : 0.18033688f;   // Q: 0.125 * log2(e)
    #pragma unroll
    for (int fi = 0; fi < 4; ++fi)
      #pragma unroll
      for (int fj = 0; fj < 4; ++fj) {
        const int n = nloc + 64 * wc + 16 * fj + i;
        #pragma unroll
        for (int r = 0; r < 4; ++r) {
          const int m = bm + 64 * wr + 16 * fi + 4 * g + r;
          Y[(size_t)m * Dsz + n] = f2bf_fast(acc[fi][fj][r] * sc);
        }
      }
  } else {
    #pragma unroll
    for (int fi = 0; fi < 4; ++fi)
      #pragma unroll
      for (int fj = 0; fj < 4; ++fj) {
        const int m0 = bm + 64 * wr + 16 * fi + 4 * g;
        const int bb = m0 >> 10;
        const int t  = m0 & 1023;
        const int n  = nloc + 64 * wc + 16 * fj + i;
        union { unsigned short u[4]; uint2 v; } pk;
        #pragma unroll
        for (int r = 0; r < 4; ++r) pk.u[r] = f2bf_fast(acc[fi][fj][r]);
        *(uint2*)&Yvt[((size_t)(bb * Dsz + n)) * Tsz + t] = pk.v;
      }
  }
}

// ---------------- output projection: out = ctx * Wp^T + bp (fp32 out) ----
__global__ __launch_bounds__(256) void gemm_proj_kernel(
    const unsigned short* __restrict__ X, const unsigned short* __restrict__ W,
    const float* __restrict__ bias, float* __restrict__ Y) {
  __shared__ __align__(16) unsigned short As[128 * 32];
  __shared__ __align__(16) unsigned short Bs[128 * 32];
  const int tid = threadIdx.x;
  const int w = tid >> 6, lane = tid & 63;
  const int i = lane & 15, g = lane >> 4;
  const int wr = w >> 1, wc = w & 1;
  const int bm = blockIdx.x * 128, bn = blockIdx.y * 128;

  f32x4_t acc[4][4];
  #pragma unroll
  for (int a = 0; a < 4; ++a)
    #pragma unroll
    for (int b2 = 0; b2 < 4; ++b2)
      #pragma unroll
      for (int r = 0; r < 4; ++r) acc[a][b2][r] = 0.f;

  for (int k0 = 0; k0 < Dsz; k0 += 32) {
    __syncthreads();
    #pragma unroll
    for (int j = 0; j < 2; ++j) {
      const int c = 2 * w + j;
      const int row = 16 * c + (lane >> 2);
      const int cb = (lane & 3) * 16;
      gload16((const char*)X + ((size_t)(bm + row) * Dsz + k0) * 2 + cb,
              (const char*)As + c * 1024);
      gload16((const char*)W + ((size_t)(bn + row) * Dsz + k0) * 2 + cb,
              (const char*)Bs + c * 1024);
    }
    __syncthreads();
    bf16x8_t af[4], bfr[4];
    #pragma unroll
    for (int f = 0; f < 4; ++f) {
      af[f]  = *(const bf16x8_t*)&As[(64 * wr + 16 * f + i) * 32 + 8 * g];
      bfr[f] = *(const bf16x8_t*)&Bs[(64 * wc + 16 * f + i) * 32 + 8 * g];
    }
    #pragma unroll
    for (int a = 0; a < 4; ++a)
      #pragma unroll
      for (int b2 = 0; b2 < 4; ++b2)
        acc[a][b2] = __builtin_amdgcn_mfma_f32_16x16x32_bf16(af[a], bfr[b2], acc[a][b2], 0, 0, 0);
  }

  #pragma unroll
  for (int fi = 0; fi < 4; ++fi)
    #pragma unroll
    for (int fj = 0; fj < 4; ++fj) {
      const int n = bn + 64 * wc + 16 * fj + i;
      const float bv = bias[n];
      #pragma unroll
      for (int r = 0; r < 4; ++r) {
        const int m = bm + 64 * wr + 16 * fi + 4 * g + r;
        Y[(size_t)m * Dsz + n] = acc[fi][fj][r] + bv;
      }
    }
}

// ---------------- flash attention: 2-phase double-buffered, KVBLK=64 ------
// Q (pre-scaled, log2 units), K: [B,T,768] bf16. Vt: [B*H*64, T] bf16.
// Block handles q-tiles qtA=blockIdx.x and qtB=15-qtA as one FLAT sequence of
// qtA+qtB+2 = 17 KV-tiles; tile t+1 is staged (global_load_lds, async) while
// tile t computes -> exactly one __syncthreads per tile.
__global__ __launch_bounds__(256) void attn_mfma_kernel(
    const unsigned short* __restrict__ Qm, const unsigned short* __restrict__ Km,
    const unsigned short* __restrict__ Vt, unsigned short* __restrict__ ctx) {
  __shared__ __align__(16) unsigned short Ks[2][64 * 64];  // [buf][key][hd] 128B rows
  __shared__ __align__(16) unsigned short Vs[2][64 * 64];  // [buf][hd][key] 128B rows
  __shared__ __align__(16) unsigned short Ps[4][16 * 72];  // per-wave P, pad 72
  const int tid = threadIdx.x, w = tid >> 6, lane = tid & 63;
  const int i = lane & 15, g = lane >> 4;
  const int bh = blockIdx.y, b = bh / Hn, h = bh % Hn;
  const int qtA = blockIdx.x, qtB = NQT - 1 - qtA;
  const int ntot = qtA + qtB + 2;   // 17

  const int sr  = lane >> 3;              // staging row-in-chunk
  const int swz = ((lane & 7) * 16) ^ (sr << 4);  // pre-swizzled source col byte

  // preload Q fragments for both q-tiles
  bf16x8_t qa[2][2];
  #pragma unroll
  for (int ts = 0; ts < 2; ++ts) {
    const int t0 = (ts ? qtB : qtA) * 64;
    const unsigned short* qp =
        Qm + ((size_t)(b * Tsz + t0 + 16 * w + i) * Dsz + h * 64 + 8 * g);
    qa[ts][0] = *(const bf16x8_t*)qp;
    qa[ts][1] = *(const bf16x8_t*)(qp + 32);
  }

  f32x4_t o[4];
  #pragma unroll
  for (int fd = 0; fd < 4; ++fd)
    #pragma unroll
    for (int r = 0; r < 4; ++r) o[fd][r] = 0.f;
  float mrun[4] = {-3.0e38f, -3.0e38f, -3.0e38f, -3.0e38f};
  float lrun[4] = {0.f, 0.f, 0.f, 0.f};

  // stage KV-tile (64 keys at kv0) into buffer p
  auto STAGE = [&](int kv0, int p) {
    #pragma unroll
    for (int j = 0; j < 2; ++j) {
      const int c = 2 * w + j;            // chunk 0..7 (8 rows x 128B each)
      const int row = 8 * c + sr;
      gload16((const char*)Km + ((size_t)(b * Tsz + kv0 + row) * Dsz + h * 64) * 2 + swz,
              (const char*)Ks[p] + c * 1024);
      gload16((const char*)Vt + ((size_t)(bh * 64 + row) * Tsz + kv0) * 2 + swz,
              (const char*)Vs[p] + c * 1024);
    }
  };

  STAGE(0, 0);

  unsigned short* Pw = &Ps[w][0];

  for (int fi = 0; fi < ntot; ++fi) {
    const int p = fi & 1;
    const int ts = (fi > qtA) ? 1 : 0;
    const int qt = ts ? qtB : qtA;
    const int t0 = qt * 64;
    const int kt = ts ? (fi - qtA - 1) : fi;

    __syncthreads();   // drains this wave's vmcnt -> tile fi staged & visible

    if (fi + 1 < ntot) {
      const int nf = fi + 1;
      const int nkt = (nf > qtA) ? (nf - qtA - 1) : nf;
      STAGE(nkt * 64, p ^ 1);            // async prefetch under compute
    }

    // S = Q K^T : lane holds S[q=4g+r][key=16fj+i]  (log2 units)
    f32x4_t s[4];
    __builtin_amdgcn_s_setprio(1);
    #pragma unroll
    for (int fj = 0; fj < 4; ++fj) {
      #pragma unroll
      for (int r = 0; r < 4; ++r) s[fj][r] = 0.f;
      const int R = 16 * fj + i;
      #pragma unroll
      for (int ks = 0; ks < 2; ++ks) {
        const bf16x8_t kb = *(const bf16x8_t*)((const char*)Ks[p] + R * 128 +
                                               ((64 * ks + 16 * g) ^ ((i & 7) << 4)));
        s[fj] = __builtin_amdgcn_mfma_f32_16x16x32_bf16(qa[ts][ks], kb, s[fj], 0, 0, 0);
      }
    }
    __builtin_amdgcn_s_setprio(0);

    // causal mask only on the diagonal tile (block-uniform)
    if (kt == qt) {
      #pragma unroll
      for (int fj = 0; fj < 4; ++fj) {
        const int kidx = kt * 64 + 16 * fj + i;
        #pragma unroll
        for (int r = 0; r < 4; ++r)
          if (kidx > t0 + 16 * w + 4 * g + r) s[fj][r] = -1.0e30f;
      }
    }

    // row max (in-lane over 4 fj, then across 16-lane groups)
    float mx[4];
    #pragma unroll
    for (int r = 0; r < 4; ++r)
      mx[r] = fmaxf(fmaxf(s[0][r], s[1][r]), fmaxf(s[2][r], s[3][r]));
    #pragma unroll
    for (int r = 0; r < 4; ++r) {
      mx[r] = fmaxf(mx[r], __shfl_xor(mx[r], 1));
      mx[r] = fmaxf(mx[r], __shfl_xor(mx[r], 2));
      mx[r] = fmaxf(mx[r], __shfl_xor(mx[r], 4));
      mx[r] = fmaxf(mx[r], __shfl_xor(mx[r], 8));
    }

    // defer-max: rescale only when max grew by >8 (log2 units)
    bool nd = false;
    #pragma unroll
    for (int r = 0; r < 4; ++r) nd = nd || (mx[r] > mrun[r] + 8.0f);
    if (__any(nd)) {
      #pragma unroll
      for (int r = 0; r < 4; ++r) {
        const float mn = fmaxf(mrun[r], mx[r]);
        const float fs = exp2f(mrun[r] - mn);
        mrun[r] = mn;
        lrun[r] *= fs;
        #pragma unroll
        for (int fd = 0; fd < 4; ++fd) o[fd][r] *= fs;
      }
    }

    float rs[4] = {0.f, 0.f, 0.f, 0.f};
    #pragma unroll
    for (int fj = 0; fj < 4; ++fj)
      #pragma unroll
      for (int r = 0; r < 4; ++r) {
        s[fj][r] = exp2f(s[fj][r] - mrun[r]);
        rs[r] += s[fj][r];
      }
    #pragma unroll
    for (int r = 0; r < 4; ++r) {
      rs[r] += __shfl_xor(rs[r], 1);
      rs[r] += __shfl_xor(rs[r], 2);
      rs[r] += __shfl_xor(rs[r], 4);
      rs[r] += __shfl_xor(rs[r], 8);
      lrun[r] += rs[r];
    }

    // stage P (bf16) into private per-wave buffer, layout D->A
    #pragma unroll
    for (int fj = 0; fj < 4; ++fj)
      #pragma unroll
      for (int r = 0; r < 4; ++r)
        Pw[(4 * g + r) * 72 + 16 * fj + i] = f2bf_fast(s[fj][r]);

    // O += P * V
    __builtin_amdgcn_s_setprio(1);
    #pragma unroll
    for (int ks = 0; ks < 2; ++ks) {
      const bf16x8_t pa = *(const bf16x8_t*)&Pw[i * 72 + 32 * ks + 8 * g];
      #pragma unroll
      for (int fd = 0; fd < 4; ++fd) {
        const int R = 16 * fd + i;
        const bf16x8_t vb = *(const bf16x8_t*)((const char*)Vs[p] + R * 128 +
                                               ((64 * ks + 16 * g) ^ ((i & 7) << 4)));
        o[fd] = __builtin_amdgcn_mfma_f32_16x16x32_bf16(pa, vb, o[fd], 0, 0, 0);
      }
    }
    __builtin_amdgcn_s_setprio(0);

    // end of first q-tile: write out, reset state
    if (fi == qtA) {
      #pragma unroll
      for (int r = 0; r < 4; ++r) {
        const float inv = 1.f / lrun[r];
        const int qidx = t0 + 16 * w + 4 * g + r;
        #pragma unroll
        for (int fd = 0; fd < 4; ++fd)
          ctx[(size_t)(b * Tsz + qidx) * Dsz + h * 64 + 16 * fd + i] =
              f2bf_fast(o[fd][r] * inv);
      }
      #pragma unroll
      for (int fd = 0; fd < 4; ++fd)
        #pragma unroll
        for (int r = 0; r < 4; ++r) o[fd][r] = 0.f;
      #pragma unroll
      for (int r = 0; r < 4; ++r) { mrun[r] = -3.0e38f; lrun[r] = 0.f; }
    }
  }

  // finalize second q-tile
  {
    const int t0 = qtB * 64;
    #pragma unroll
    for (int r = 0; r < 4; ++r) {
      const float inv = 1.f / lrun[r];
      const int qidx = t0 + 16 * w + 4 * g + r;
      #pragma unroll
      for (int fd = 0; fd < 4; ++fd)
        ctx[(size_t)(b * Tsz + qidx) * Dsz + h * 64 + 16 * fd + i] =
            f2bf_fast(o[fd][r] * inv);
    }
  }
}

extern "C" void kernel_launch(void* const* d_in, const int* in_sizes, int n_in,
                              void* d_out, int out_size, void* d_ws, size_t ws_size,
                              hipStream_t stream) {
  const float* x  = (const float*)d_in[0];
  const float* Wq = (const float*)d_in[1];
  const float* Wk = (const float*)d_in[2];
  const float* Wv = (const float*)d_in[3];
  const float* Wp = (const float*)d_in[4];
  const float* bp = (const float*)d_in[5];
  float* out = (float*)d_out;

  const size_t md = (size_t)Msz * Dsz;
  const size_t wd = (size_t)Dsz * Dsz;
  unsigned short* xb   = (unsigned short*)d_ws;
  unsigned short* wqb  = xb + md;          // wqb,wkb,wvb contiguous = Wcat[2304][768]
  unsigned short* wkb  = wqb + wd;
  unsigned short* wvb  = wkb + wd;
  unsigned short* wpb  = wvb + wd;
  unsigned short* qb   = wpb + wd;
  unsigned short* kb   = qb + md;
  unsigned short* vtb  = kb + md;
  unsigned short* ctxb = vtb + md;

  cvt_all_kernel<<<XBLKS + 4 * WBLKS, 256, 0, stream>>>(
      x, Wq, Wk, Wv, Wp, xb, wqb, wkb, wvb, wpb);

  gemm_qkv_kernel<<<dim3(Msz / 128, 18), 256, 0, stream>>>(xb, wqb, qb, kb, vtb);

  attn_mfma_kernel<<<dim3(NQT / 2, Bsz * Hn), 256, 0, stream>>>(qb, kb, vtb, ctxb);

  gemm_proj_kernel<<<dim3(Msz / 128, Dsz / 128), 256, 0, stream>>>(ctxb, wpb, bp, out);
}